// Round 8
// baseline (7197.707 us; speedup 1.0000x reference)
//
#include <hip/hip_runtime.h>
#include <hip/hip_fp16.h>
#include <math.h>

#define NB 16
#define NA 720
#define ND 1024
#define NH 512
#define NW 512

#define TW 64      // tile width  (x)
#define TH 32      // tile height (y)
#define PXT 8      // y-pixels per thread
#define WINN 96    // window entries/batch (span <= sqrt(63^2+31^2)+3 ~ 73)
#define GROUP 16   // angles per fp16-accumulate group (720 = 45*16)

typedef __fp16 h2vec __attribute__((ext_vector_type(2)));

__device__ __forceinline__ uint32_t pkrtz_u32(float a, float b) {
    union { h2vec h; uint32_t u; } v;
    v.h = __builtin_amdgcn_cvt_pkrtz(a, b);   // one v_cvt_pkrtz_f16_f32
    return v.u;
}
__device__ __forceinline__ __half2 u32_to_h2(uint32_t u) {
    union { uint32_t u; __half2 h; } v; v.u = u; return v.h;
}

// ---------------------------------------------------------------------------
// Kernel 0: per-angle cos/sin table (matches jnp.linspace(0, pi, A, endpoint=False))
// ---------------------------------------------------------------------------
__global__ __launch_bounds__(256) void angle_kernel(float2* __restrict__ cs) {
    int a = blockIdx.x * 256 + threadIdx.x;
    if (a < NA) {
        const float step = (float)(M_PI / (double)NA);
        float ang = (float)a * step;
        float s, c;
        sincosf(ang, &s, &c);
        cs[a] = make_float2(c, s);
    }
}

// ---------------------------------------------------------------------------
// Kernel 1: ramp filter via in-LDS Stockham radix-2 FFT (fp32), TWO real rows
// per block packed as z = x0 + i*x1. Filter is real & even-symmetric, so
// Y = filt*Z directly; IFFT gives y0 = Re, y1 = Im. 1/ND ifft-norm folded in
// (pi/NA applied at backproj epilogue to keep fp16 staging well-scaled).
// ---------------------------------------------------------------------------
__global__ __launch_bounds__(256) void filter_kernel(const float* __restrict__ sino,
                                                     const float* __restrict__ filt,
                                                     float* __restrict__ outp) {
    __shared__ float2 bufA[ND];
    __shared__ float2 bufB[ND];
    __shared__ float2 tw[ND / 2];   // tw[m] = exp(-2*pi*i*m/ND)

    const int tid = threadIdx.x;
    const size_t r0 = (size_t)blockIdx.x * 2;
    const float* __restrict__ xa = sino + r0 * ND;
    const float* __restrict__ xb = xa + ND;
    float* __restrict__ ya = outp + r0 * ND;
    float* __restrict__ yb = ya + ND;

    #pragma unroll
    for (int i = 0; i < ND; i += 256)
        bufA[i + tid] = make_float2(xa[i + tid], xb[i + tid]);
    #pragma unroll
    for (int i = 0; i < ND / 2; i += 256) {
        int m = i + tid;
        float ang = (float)(-2.0 * M_PI / (double)ND) * (float)m;
        float s, c;
        sincosf(ang, &s, &c);
        tw[m] = make_float2(c, s);
    }
    __syncthreads();

    float2* src = bufA;
    float2* dst = bufB;

    // forward FFT: Stockham, Ns = 1..512
    for (int Ns = 1; Ns < ND; Ns <<= 1) {
        #pragma unroll
        for (int q = 0; q < ND / 2; q += 256) {
            int j = q + tid;
            int m = j & (Ns - 1);
            float2 v0 = src[j];
            float2 v1 = src[j + ND / 2];
            float2 w = tw[m * (ND / 2 / Ns)];
            float tr = w.x * v1.x - w.y * v1.y;
            float ti = w.x * v1.y + w.y * v1.x;
            int d = ((j & ~(Ns - 1)) << 1) + m;
            dst[d]      = make_float2(v0.x + tr, v0.y + ti);
            dst[d + Ns] = make_float2(v0.x - tr, v0.y - ti);
        }
        __syncthreads();
        float2* tmp = src; src = dst; dst = tmp;
    }

    // multiply by real filter, with 1/ND folded in
    const float SCALE = 1.0f / (float)ND;
    #pragma unroll
    for (int i = 0; i < ND; i += 256) {
        float f = filt[i + tid] * SCALE;
        src[i + tid].x *= f;
        src[i + tid].y *= f;
    }
    __syncthreads();

    // inverse FFT: same flow with conjugated twiddles
    for (int Ns = 1; Ns < ND; Ns <<= 1) {
        #pragma unroll
        for (int q = 0; q < ND / 2; q += 256) {
            int j = q + tid;
            int m = j & (Ns - 1);
            float2 v0 = src[j];
            float2 v1 = src[j + ND / 2];
            float2 w = tw[m * (ND / 2 / Ns)];
            float tr = w.x * v1.x + w.y * v1.y;   // conj(w)*v1
            float ti = w.x * v1.y - w.y * v1.x;
            int d = ((j & ~(Ns - 1)) << 1) + m;
            dst[d]      = make_float2(v0.x + tr, v0.y + ti);
            dst[d + Ns] = make_float2(v0.x - tr, v0.y - ti);
        }
        __syncthreads();
        float2* tmp = src; src = dst; dst = tmp;
    }

    #pragma unroll
    for (int i = 0; i < ND; i += 256) {
        ya[i + tid] = src[i + tid].x;   // row r0   (Re)
        yb[i + tid] = src[i + tid].y;   // row r0+1 (Im)
    }
}

// ---------------------------------------------------------------------------
// Kernel 2: backprojection. 64x32 tile x 2 BATCHES per 256-thread block,
// PXT=8 y-px/thread -> per-angle overhead (params, staging, barrier) is
// amortized over 2x the samples of R7. Window entry i = 8B, batch-paired
// fp16: word0 = (h(f_b0), h(f_b1)), word1 = (h(df_b0), h(df_b1)); one
// ds_read_b64 + v_pk_add_f16 + v_pk_fma_f16 per 2 samples. FOUR window
// phases, 2 angles computed per barrier round (360 barriers, not 720):
// round r computes angles a,a+1 from phases r&3,(r+1)&3 while 192 threads
// stage a+2,a+3 into the other two phases. fp16 accumulator flushed to
// fp32 every GROUP=16 angles. Bounds check eliminated:
// |px*c+py*s| <= 361.3 < 511.5; local index in [1,74] subset of [0,94].
// ---------------------------------------------------------------------------
__global__ __launch_bounds__(256, 4) void backproj_kernel(const float* __restrict__ filtered,
                                                          const float2* __restrict__ cs_tab,
                                                          float* __restrict__ img) {
    __shared__ __align__(16) uint2 win[4][WINN];   // 3 KB

    const int tid = threadIdx.x;
    const int bx = blockIdx.x, by = blockIdx.y, bz = blockIdx.z;

    const float x0 = (float)(bx * TW) - 255.5f;
    const float x1 = x0 + (float)(TW - 1);
    const float y0 = (float)(by * TH) - 255.5f;

    // per-angle params, block-uniform: (c, s, 511.5-base, bits(a*ND+base))
    // s >= 0 for angles in [0, pi) -> min over y at y0.
    auto calc_params = [&](int a) -> float4 {
        float2 cs = cs_tab[a];
        float tmin = 511.5f + fminf(x0 * cs.x, x1 * cs.x) + y0 * cs.y;
        int base = (int)floorf(tmin) - 1;
        return make_float4(cs.x, cs.y, 511.5f - (float)base,
                           __int_as_float(a * ND + base));
    };

    // staging: tids 0..95 stage the even prefetch angle, 96..191 the odd one
    const bool stg = tid < 2 * WINN;
    const int sg   = (tid >= WINN) ? 1 : 0;
    const int si   = tid - sg * WINN;
    const float* __restrict__ srow0 =
        filtered + (size_t)(bz * 2) * NA * ND + si;
    const float* __restrict__ srow1 = srow0 + (size_t)NA * ND;

    const int tx  = tid & (TW - 1);
    const int ty0 = (tid >> 6) * PXT;
    const float px  = (float)(bx * TW + tx)  - 255.5f;
    const float pyf = (float)(by * TH + ty0) - 255.5f;

    float acc0[PXT], acc1[PXT];
    __half2 hacc[PXT];
    #pragma unroll
    for (int k = 0; k < PXT; k++) {
        acc0[k] = 0.0f; acc1[k] = 0.0f; hacc[k] = u32_to_h2(0u);
    }

    // prologue: stage angles 0 and 1 into phases 0 and 1
    float4 P0 = calc_params(0);
    float4 P1 = calc_params(1);
    if (stg) {
        float4 Ps = sg ? P1 : P0;
        int soff = __float_as_int(Ps.w);
        float f0 = srow0[soff], f0n = srow0[soff + 1];
        float f1 = srow1[soff], f1n = srow1[soff + 1];
        win[sg][si] = make_uint2(pkrtz_u32(f0, f1),
                                 pkrtz_u32(f0n - f0, f1n - f1));
    }
    __syncthreads();

    for (int grp = 0; grp < NA; grp += GROUP) {
        #pragma unroll
        for (int r = 0; r < GROUP; r += 2) {      // r compile-time -> phases imm
            const int a0 = grp + r;

            // prefetch params + issue staging loads for angles a0+2, a0+3
            float4 P2 = P0, P3 = P1;
            uint2 sv = make_uint2(0u, 0u);
            const bool pre = (a0 + 2 < NA);
            if (pre) {
                P2 = calc_params(a0 + 2);
                P3 = calc_params(a0 + 3);
                if (stg) {
                    float4 Ps = sg ? P3 : P2;
                    int soff = __float_as_int(Ps.w);
                    float f0 = srow0[soff], f0n = srow0[soff + 1];
                    float f1 = srow1[soff], f1n = srow1[soff + 1];
                    sv = make_uint2(pkrtz_u32(f0, f1),
                                    pkrtz_u32(f0n - f0, f1n - f1));
                }
            }

            // compute angle a0 from phase r&3
            {
                const float sy = P0.y;
                const float tb = fmaf(px, P0.x, fmaf(pyf, sy, P0.z));
                #pragma unroll
                for (int k = 0; k < PXT; k++) {
                    float t  = fmaf((float)k, sy, tb);
                    int   i0 = (int)t;
#if __has_builtin(__builtin_amdgcn_fractf)
                    float w  = __builtin_amdgcn_fractf(t);
#else
                    float w  = t - (float)i0;
#endif
                    __half2 wh2 = u32_to_h2(pkrtz_u32(w, w));
                    const uint2 pk = win[r & 3][i0];
                    hacc[k] = __hadd2(hacc[k], u32_to_h2(pk.x));
                    hacc[k] = __hfma2(wh2, u32_to_h2(pk.y), hacc[k]);
                }
            }
            // compute angle a0+1 from phase (r+1)&3
            {
                const float sy = P1.y;
                const float tb = fmaf(px, P1.x, fmaf(pyf, sy, P1.z));
                #pragma unroll
                for (int k = 0; k < PXT; k++) {
                    float t  = fmaf((float)k, sy, tb);
                    int   i0 = (int)t;
#if __has_builtin(__builtin_amdgcn_fractf)
                    float w  = __builtin_amdgcn_fractf(t);
#else
                    float w  = t - (float)i0;
#endif
                    __half2 wh2 = u32_to_h2(pkrtz_u32(w, w));
                    const uint2 pk = win[(r + 1) & 3][i0];
                    hacc[k] = __hadd2(hacc[k], u32_to_h2(pk.x));
                    hacc[k] = __hfma2(wh2, u32_to_h2(pk.y), hacc[k]);
                }
            }

            if (pre && stg)
                win[(r + 2 + sg) & 3][si] = sv;
            P0 = P2;
            P1 = P3;
            __syncthreads();
        }
        // flush fp16 group accumulator into fp32
        #pragma unroll
        for (int k = 0; k < PXT; k++) {
            float2 v = __half22float2(hacc[k]);
            acc0[k] += v.x;
            acc1[k] += v.y;
            hacc[k] = u32_to_h2(0u);
        }
    }

    const float SCALE = (float)(M_PI / (double)NA);
    size_t o0 = (((size_t)(bz * 2) * NH) + (by * TH + ty0)) * NW + (bx * TW + tx);
    size_t o1 = o0 + (size_t)NH * NW;
    #pragma unroll
    for (int k = 0; k < PXT; k++) {
        img[o0 + (size_t)k * NW] = acc0[k] * SCALE;
        img[o1 + (size_t)k * NW] = acc1[k] * SCALE;
    }
}

// ---------------------------------------------------------------------------
extern "C" void kernel_launch(void* const* d_in, const int* in_sizes, int n_in,
                              void* d_out, int out_size, void* d_ws, size_t ws_size,
                              hipStream_t stream) {
    const float* sino = (const float*)d_in[0];
    const float* filt = (const float*)d_in[1];
    float* out = (float*)d_out;

    const size_t filt_bytes = (size_t)NB * NA * ND * sizeof(float);
    float* filtered;
    float2* cs_tab;
    if (ws_size >= filt_bytes + 4096) {
        filtered = (float*)d_ws;
        cs_tab = (float2*)((char*)d_ws + filt_bytes);
    } else {
        // fallback: filter in-place into the input (harness restores inputs
        // from a pristine copy before every launch)
        filtered = (float*)d_in[0];
        cs_tab = (float2*)d_ws;
    }

    angle_kernel<<<dim3(3), dim3(256), 0, stream>>>(cs_tab);
    filter_kernel<<<dim3(NB * NA / 2), dim3(256), 0, stream>>>(sino, filt, filtered);
    backproj_kernel<<<dim3(NW / TW, NH / TH, NB / 2), dim3(256), 0, stream>>>(filtered, cs_tab, out);
}

// Round 9
// 676.228 us; speedup vs baseline: 10.6439x; 10.6439x over previous
//
#include <hip/hip_runtime.h>
#include <hip/hip_fp16.h>
#include <math.h>

#define NB 16
#define NA 720
#define ND 1024
#define NH 512
#define NW 512

#define TW 64      // tile width  (x)
#define TH 32      // tile height (y)
#define PXT 8      // y-pixels per thread
#define WINN 96    // window entries/batch (span <= sqrt(63^2+31^2)+3 ~ 73)
#define GROUP 16   // angles per fp16-accumulate group (720 = 45*16)

typedef __fp16 h2vec __attribute__((ext_vector_type(2)));

__device__ __forceinline__ uint32_t pkrtz_u32(float a, float b) {
    union { h2vec h; uint32_t u; } v;
    v.h = __builtin_amdgcn_cvt_pkrtz(a, b);   // one v_cvt_pkrtz_f16_f32
    return v.u;
}
__device__ __forceinline__ __half2 u32_to_h2(uint32_t u) {
    union { uint32_t u; __half2 h; } v; v.u = u; return v.h;
}

// ---------------------------------------------------------------------------
// Kernel 0: per-angle cos/sin table (matches jnp.linspace(0, pi, A, endpoint=False))
// ---------------------------------------------------------------------------
__global__ __launch_bounds__(256) void angle_kernel(float2* __restrict__ cs) {
    int a = blockIdx.x * 256 + threadIdx.x;
    if (a < NA) {
        const float step = (float)(M_PI / (double)NA);
        float ang = (float)a * step;
        float s, c;
        sincosf(ang, &s, &c);
        cs[a] = make_float2(c, s);
    }
}

// ---------------------------------------------------------------------------
// Kernel 1: ramp filter via in-LDS Stockham radix-2 FFT (fp32), TWO real rows
// per block packed as z = x0 + i*x1. Filter is real & even-symmetric, so
// Y = filt*Z directly; IFFT gives y0 = Re, y1 = Im. 1/ND ifft-norm folded in
// (pi/NA applied at backproj epilogue to keep fp16 staging well-scaled).
// ---------------------------------------------------------------------------
__global__ __launch_bounds__(256) void filter_kernel(const float* __restrict__ sino,
                                                     const float* __restrict__ filt,
                                                     float* __restrict__ outp) {
    __shared__ float2 bufA[ND];
    __shared__ float2 bufB[ND];
    __shared__ float2 tw[ND / 2];   // tw[m] = exp(-2*pi*i*m/ND)

    const int tid = threadIdx.x;
    const size_t r0 = (size_t)blockIdx.x * 2;
    const float* __restrict__ xa = sino + r0 * ND;
    const float* __restrict__ xb = xa + ND;
    float* __restrict__ ya = outp + r0 * ND;
    float* __restrict__ yb = ya + ND;

    #pragma unroll
    for (int i = 0; i < ND; i += 256)
        bufA[i + tid] = make_float2(xa[i + tid], xb[i + tid]);
    #pragma unroll
    for (int i = 0; i < ND / 2; i += 256) {
        int m = i + tid;
        float ang = (float)(-2.0 * M_PI / (double)ND) * (float)m;
        float s, c;
        sincosf(ang, &s, &c);
        tw[m] = make_float2(c, s);
    }
    __syncthreads();

    float2* src = bufA;
    float2* dst = bufB;

    // forward FFT: Stockham, Ns = 1..512
    for (int Ns = 1; Ns < ND; Ns <<= 1) {
        #pragma unroll
        for (int q = 0; q < ND / 2; q += 256) {
            int j = q + tid;
            int m = j & (Ns - 1);
            float2 v0 = src[j];
            float2 v1 = src[j + ND / 2];
            float2 w = tw[m * (ND / 2 / Ns)];
            float tr = w.x * v1.x - w.y * v1.y;
            float ti = w.x * v1.y + w.y * v1.x;
            int d = ((j & ~(Ns - 1)) << 1) + m;
            dst[d]      = make_float2(v0.x + tr, v0.y + ti);
            dst[d + Ns] = make_float2(v0.x - tr, v0.y - ti);
        }
        __syncthreads();
        float2* tmp = src; src = dst; dst = tmp;
    }

    // multiply by real filter, with 1/ND folded in
    const float SCALE = 1.0f / (float)ND;
    #pragma unroll
    for (int i = 0; i < ND; i += 256) {
        float f = filt[i + tid] * SCALE;
        src[i + tid].x *= f;
        src[i + tid].y *= f;
    }
    __syncthreads();

    // inverse FFT: same flow with conjugated twiddles
    for (int Ns = 1; Ns < ND; Ns <<= 1) {
        #pragma unroll
        for (int q = 0; q < ND / 2; q += 256) {
            int j = q + tid;
            int m = j & (Ns - 1);
            float2 v0 = src[j];
            float2 v1 = src[j + ND / 2];
            float2 w = tw[m * (ND / 2 / Ns)];
            float tr = w.x * v1.x + w.y * v1.y;   // conj(w)*v1
            float ti = w.x * v1.y - w.y * v1.x;
            int d = ((j & ~(Ns - 1)) << 1) + m;
            dst[d]      = make_float2(v0.x + tr, v0.y + ti);
            dst[d + Ns] = make_float2(v0.x - tr, v0.y - ti);
        }
        __syncthreads();
        float2* tmp = src; src = dst; dst = tmp;
    }

    #pragma unroll
    for (int i = 0; i < ND; i += 256) {
        ya[i + tid] = src[i + tid].x;   // row r0   (Re)
        yb[i + tid] = src[i + tid].y;   // row r0+1 (Im)
    }
}

// ---------------------------------------------------------------------------
// Kernel 2: backprojection. 64x32 tile x 2 BATCHES per 256-thread block,
// PXT=8 y-px/thread: per-angle overhead (params/staging/barrier) amortized
// over 1024 samples per block-angle. EXACT R7 loop structure (2 phases,
// 1 angle per barrier, compile-time phase, shallow unroll) — R8's 16-angle
// unrolled body caused accumulator scratch-spill (13.8 GB WRITE_SIZE).
// Window entry i = 8B batch-paired fp16: word0=(h(f_b0),h(f_b1)),
// word1=(h(df_b0),h(df_b1)); one ds_read_b64 + v_pk_add_f16 + v_pk_fma_f16
// per 2 samples. fp16 acc flushed to fp32 every GROUP=16 angles
// (group |sum| <= ~48, fp16-safe). Bounds check eliminated:
// |px*c+py*s| <= 361.3 < 511.5; local index in [1,75] subset of [0,94].
// ---------------------------------------------------------------------------
__global__ __launch_bounds__(256, 4) void backproj_kernel(const float* __restrict__ filtered,
                                                          const float2* __restrict__ cs_tab,
                                                          float* __restrict__ img) {
    __shared__ __align__(16) uint2 win[2][WINN];   // 1.5 KB

    const int tid = threadIdx.x;
    const int bx = blockIdx.x, by = blockIdx.y, bz = blockIdx.z;

    const float x0 = (float)(bx * TW) - 255.5f;
    const float x1 = x0 + (float)(TW - 1);
    const float y0 = (float)(by * TH) - 255.5f;

    // per-angle params, block-uniform: (c, s, 511.5-base, bits(a*ND+base))
    // s >= 0 for angles in [0, pi) -> min over y at y0.
    auto calc_params = [&](int a) -> float4 {
        float2 cs = cs_tab[a];
        float tmin = 511.5f + fminf(x0 * cs.x, x1 * cs.x) + y0 * cs.y;
        int base = (int)floorf(tmin) - 1;
        return make_float4(cs.x, cs.y, 511.5f - (float)base,
                           __int_as_float(a * ND + base));
    };

    // staging: threads 0..WINN-1 each build one full 8B entry (both batches)
    const bool stg = tid < WINN;
    const float* __restrict__ srow0 =
        filtered + (size_t)(bz * 2) * NA * ND + tid;
    const float* __restrict__ srow1 = srow0 + (size_t)NA * ND;

    const int tx  = tid & (TW - 1);
    const int ty0 = (tid >> 6) * PXT;
    const float px  = (float)(bx * TW + tx)  - 255.5f;
    const float pyf = (float)(by * TH + ty0) - 255.5f;

    float acc0[PXT], acc1[PXT];
    __half2 hacc[PXT];
    #pragma unroll
    for (int k = 0; k < PXT; k++) {
        acc0[k] = 0.0f; acc1[k] = 0.0f; hacc[k] = u32_to_h2(0u);
    }

    // prologue: stage angle 0 into phase 0
    float4 P = calc_params(0);
    if (stg) {
        int soff = __float_as_int(P.w);
        float f0 = srow0[soff], f0n = srow0[soff + 1];
        float f1 = srow1[soff], f1n = srow1[soff + 1];
        win[0][tid] = make_uint2(pkrtz_u32(f0, f1),
                                 pkrtz_u32(f0n - f0, f1n - f1));
    }
    __syncthreads();

    for (int g = 0; g < NA; g += GROUP) {
        for (int a0 = 0; a0 < GROUP; a0 += 2) {
            #pragma unroll
            for (int p = 0; p < 2; p++) {
                const int a = g + a0 + p;
                float4 Pn = P;
                uint2 stage_val = make_uint2(0u, 0u);
                const bool pre = (a + 1 < NA);
                if (pre) {
                    Pn = calc_params(a + 1);
                    if (stg) {
                        int soff = __float_as_int(Pn.w);
                        float f0 = srow0[soff], f0n = srow0[soff + 1];
                        float f1 = srow1[soff], f1n = srow1[soff + 1];
                        stage_val = make_uint2(pkrtz_u32(f0, f1),
                                               pkrtz_u32(f0n - f0, f1n - f1));
                    }
                }

                const float sy = P.y;
                const float tb = fmaf(px, P.x, fmaf(pyf, sy, P.z));
                #pragma unroll
                for (int k = 0; k < PXT; k++) {
                    float t  = fmaf((float)k, sy, tb);
                    int   i0 = (int)t;                    // t > 0 -> trunc == floor
#if __has_builtin(__builtin_amdgcn_fractf)
                    float w  = __builtin_amdgcn_fractf(t);
#else
                    float w  = t - (float)i0;
#endif
                    __half2 wh2 = u32_to_h2(pkrtz_u32(w, w));   // one pkrtz
                    const uint2 pk = win[p][i0];                // ds_read_b64
                    hacc[k] = __hadd2(hacc[k], u32_to_h2(pk.x));          // += (f0,f1)
                    hacc[k] = __hfma2(wh2, u32_to_h2(pk.y), hacc[k]);     // += w*(df0,df1)
                }

                if (pre && stg)
                    win[p ^ 1][tid] = stage_val;
                P = Pn;
                __syncthreads();
            }
        }
        // flush fp16 group accumulator into fp32
        #pragma unroll
        for (int k = 0; k < PXT; k++) {
            float2 v = __half22float2(hacc[k]);
            acc0[k] += v.x;
            acc1[k] += v.y;
            hacc[k] = u32_to_h2(0u);
        }
    }

    const float SCALE = (float)(M_PI / (double)NA);
    size_t o0 = (((size_t)(bz * 2) * NH) + (by * TH + ty0)) * NW + (bx * TW + tx);
    size_t o1 = o0 + (size_t)NH * NW;
    #pragma unroll
    for (int k = 0; k < PXT; k++) {
        img[o0 + (size_t)k * NW] = acc0[k] * SCALE;
        img[o1 + (size_t)k * NW] = acc1[k] * SCALE;
    }
}

// ---------------------------------------------------------------------------
extern "C" void kernel_launch(void* const* d_in, const int* in_sizes, int n_in,
                              void* d_out, int out_size, void* d_ws, size_t ws_size,
                              hipStream_t stream) {
    const float* sino = (const float*)d_in[0];
    const float* filt = (const float*)d_in[1];
    float* out = (float*)d_out;

    const size_t filt_bytes = (size_t)NB * NA * ND * sizeof(float);
    float* filtered;
    float2* cs_tab;
    if (ws_size >= filt_bytes + 4096) {
        filtered = (float*)d_ws;
        cs_tab = (float2*)((char*)d_ws + filt_bytes);
    } else {
        // fallback: filter in-place into the input (harness restores inputs
        // from a pristine copy before every launch)
        filtered = (float*)d_in[0];
        cs_tab = (float2*)d_ws;
    }

    angle_kernel<<<dim3(3), dim3(256), 0, stream>>>(cs_tab);
    filter_kernel<<<dim3(NB * NA / 2), dim3(256), 0, stream>>>(sino, filt, filtered);
    backproj_kernel<<<dim3(NW / TW, NH / TH, NB / 2), dim3(256), 0, stream>>>(filtered, cs_tab, out);
}

// Round 10
// 620.141 us; speedup vs baseline: 11.6066x; 1.0904x over previous
//
#include <hip/hip_runtime.h>
#include <hip/hip_fp16.h>
#include <math.h>

#define NB 16
#define NA 720
#define ND 1024
#define NH 512
#define NW 512

#define TW 64      // tile width  (x)
#define TH 16      // tile height (y)
#define PXT 4      // y-pixels per thread
#define NBT 4      // batches per block
#define WINN 96    // window entries/batch (span <= sqrt(63^2+15^2)+3 ~ 68)
#define GROUP 16   // angles per fp16-accumulate group (720 = 45*16)

typedef __fp16 h2vec __attribute__((ext_vector_type(2)));

__device__ __forceinline__ uint32_t pkrtz_u32(float a, float b) {
    union { h2vec h; uint32_t u; } v;
    v.h = __builtin_amdgcn_cvt_pkrtz(a, b);   // one v_cvt_pkrtz_f16_f32
    return v.u;
}
__device__ __forceinline__ __half2 u32_to_h2(uint32_t u) {
    union { uint32_t u; __half2 h; } v; v.u = u; return v.h;
}

// ---------------------------------------------------------------------------
// Kernel 0: per-angle cos/sin table (matches jnp.linspace(0, pi, A, endpoint=False))
// ---------------------------------------------------------------------------
__global__ __launch_bounds__(256) void angle_kernel(float2* __restrict__ cs) {
    int a = blockIdx.x * 256 + threadIdx.x;
    if (a < NA) {
        const float step = (float)(M_PI / (double)NA);
        float ang = (float)a * step;
        float s, c;
        sincosf(ang, &s, &c);
        cs[a] = make_float2(c, s);
    }
}

// ---------------------------------------------------------------------------
// Kernel 1: ramp filter via in-LDS Stockham radix-2 FFT (fp32), TWO real rows
// per block packed as z = x0 + i*x1. Filter is real & even-symmetric, so
// Y = filt*Z directly; IFFT gives y0 = Re, y1 = Im. 1/ND ifft-norm folded in
// (pi/NA applied at backproj epilogue to keep fp16 staging well-scaled).
// ---------------------------------------------------------------------------
__global__ __launch_bounds__(256) void filter_kernel(const float* __restrict__ sino,
                                                     const float* __restrict__ filt,
                                                     float* __restrict__ outp) {
    __shared__ float2 bufA[ND];
    __shared__ float2 bufB[ND];
    __shared__ float2 tw[ND / 2];   // tw[m] = exp(-2*pi*i*m/ND)

    const int tid = threadIdx.x;
    const size_t r0 = (size_t)blockIdx.x * 2;
    const float* __restrict__ xa = sino + r0 * ND;
    const float* __restrict__ xb = xa + ND;
    float* __restrict__ ya = outp + r0 * ND;
    float* __restrict__ yb = ya + ND;

    #pragma unroll
    for (int i = 0; i < ND; i += 256)
        bufA[i + tid] = make_float2(xa[i + tid], xb[i + tid]);
    #pragma unroll
    for (int i = 0; i < ND / 2; i += 256) {
        int m = i + tid;
        float ang = (float)(-2.0 * M_PI / (double)ND) * (float)m;
        float s, c;
        sincosf(ang, &s, &c);
        tw[m] = make_float2(c, s);
    }
    __syncthreads();

    float2* src = bufA;
    float2* dst = bufB;

    // forward FFT: Stockham, Ns = 1..512
    for (int Ns = 1; Ns < ND; Ns <<= 1) {
        #pragma unroll
        for (int q = 0; q < ND / 2; q += 256) {
            int j = q + tid;
            int m = j & (Ns - 1);
            float2 v0 = src[j];
            float2 v1 = src[j + ND / 2];
            float2 w = tw[m * (ND / 2 / Ns)];
            float tr = w.x * v1.x - w.y * v1.y;
            float ti = w.x * v1.y + w.y * v1.x;
            int d = ((j & ~(Ns - 1)) << 1) + m;
            dst[d]      = make_float2(v0.x + tr, v0.y + ti);
            dst[d + Ns] = make_float2(v0.x - tr, v0.y - ti);
        }
        __syncthreads();
        float2* tmp = src; src = dst; dst = tmp;
    }

    // multiply by real filter, with 1/ND folded in
    const float SCALE = 1.0f / (float)ND;
    #pragma unroll
    for (int i = 0; i < ND; i += 256) {
        float f = filt[i + tid] * SCALE;
        src[i + tid].x *= f;
        src[i + tid].y *= f;
    }
    __syncthreads();

    // inverse FFT: same flow with conjugated twiddles
    for (int Ns = 1; Ns < ND; Ns <<= 1) {
        #pragma unroll
        for (int q = 0; q < ND / 2; q += 256) {
            int j = q + tid;
            int m = j & (Ns - 1);
            float2 v0 = src[j];
            float2 v1 = src[j + ND / 2];
            float2 w = tw[m * (ND / 2 / Ns)];
            float tr = w.x * v1.x + w.y * v1.y;   // conj(w)*v1
            float ti = w.x * v1.y - w.y * v1.x;
            int d = ((j & ~(Ns - 1)) << 1) + m;
            dst[d]      = make_float2(v0.x + tr, v0.y + ti);
            dst[d + Ns] = make_float2(v0.x - tr, v0.y - ti);
        }
        __syncthreads();
        float2* tmp = src; src = dst; dst = tmp;
    }

    #pragma unroll
    for (int i = 0; i < ND; i += 256) {
        ya[i + tid] = src[i + tid].x;   // row r0   (Re)
        yb[i + tid] = src[i + tid].y;   // row r0+1 (Im)
    }
}

// ---------------------------------------------------------------------------
// Kernel 2: backprojection. 64x16 tile x 4 BATCHES per 256-thread block.
// Window entry i = 16B uint4, batch-paired fp16:
//   x=(h f_b0, h f_b1)  y=(h df_b0, h df_b1)  z=(h f_b2, h f_b3)  w=(h df_b2, h df_b3)
// ONE ds_read_b128 + 2x v_pk_add_f16 + 2x v_pk_fma_f16 serve FOUR batches'
// lerp-accumulates (~2.25 VALU/sample, was 3.5 in R9). R9 loop skeleton kept
// (2 phases, 1 angle/barrier, compile-time phase, shallow unroll — R8's deep
// unroll spilled). Staging: 192 threads, sg=tid/96 handles batch pair 2sg,
// one ds_write_b64 per thread. fp16 acc flushed to fp32 every GROUP=16
// angles (group |sum| <= ~48, fp16-safe). Bounds check eliminated:
// |px*c+py*s| <= 361.3 < 511.5; local index in [1,70] subset of [0,94].
// ---------------------------------------------------------------------------
__global__ __launch_bounds__(256, 4) void backproj_kernel(const float* __restrict__ filtered,
                                                          const float2* __restrict__ cs_tab,
                                                          float* __restrict__ img) {
    __shared__ __align__(16) uint4 win[2][WINN];   // 3 KB

    const int tid = threadIdx.x;
    const int bx = blockIdx.x, by = blockIdx.y, bz = blockIdx.z;

    const float x0 = (float)(bx * TW) - 255.5f;
    const float x1 = x0 + (float)(TW - 1);
    const float y0 = (float)(by * TH) - 255.5f;

    // per-angle params, block-uniform: (c, s, 511.5-base, bits(a*ND+base))
    // s >= 0 for angles in [0, pi) -> min over y at y0.
    auto calc_params = [&](int a) -> float4 {
        float2 cs = cs_tab[a];
        float tmin = 511.5f + fminf(x0 * cs.x, x1 * cs.x) + y0 * cs.y;
        int base = (int)floorf(tmin) - 1;
        return make_float4(cs.x, cs.y, 511.5f - (float)base,
                           __int_as_float(a * ND + base));
    };

    // staging: threads 0..191; sg selects batch pair (0: b0,b1 / 1: b2,b3),
    // si = window entry. One ds_write_b64 per thread per angle.
    const bool stg = tid < 2 * WINN;
    const int sg   = (tid >= WINN) ? 1 : 0;
    const int si   = tid - sg * WINN;
    const float* __restrict__ srowA =
        filtered + (size_t)(bz * NBT + 2 * sg) * NA * ND + si;
    const float* __restrict__ srowB = srowA + (size_t)NA * ND;

    const int tx  = tid & (TW - 1);
    const int ty0 = (tid >> 6) * PXT;
    const float px  = (float)(bx * TW + tx)  - 255.5f;
    const float pyf = (float)(by * TH + ty0) - 255.5f;

    float acc0[PXT], acc1[PXT], acc2[PXT], acc3[PXT];
    __half2 hacc01[PXT], hacc23[PXT];
    #pragma unroll
    for (int k = 0; k < PXT; k++) {
        acc0[k] = 0.0f; acc1[k] = 0.0f; acc2[k] = 0.0f; acc3[k] = 0.0f;
        hacc01[k] = u32_to_h2(0u); hacc23[k] = u32_to_h2(0u);
    }

    // prologue: stage angle 0 into phase 0
    float4 P = calc_params(0);
    if (stg) {
        int soff = __float_as_int(P.w);
        float fa = srowA[soff], fan = srowA[soff + 1];
        float fb = srowB[soff], fbn = srowB[soff + 1];
        uint2 sv = make_uint2(pkrtz_u32(fa, fb),
                              pkrtz_u32(fan - fa, fbn - fb));
        ((uint2*)&win[0][si])[sg] = sv;
    }
    __syncthreads();

    for (int g = 0; g < NA; g += GROUP) {
        for (int a0 = 0; a0 < GROUP; a0 += 2) {
            #pragma unroll
            for (int p = 0; p < 2; p++) {
                const int a = g + a0 + p;
                float4 Pn = P;
                uint2 stage_val = make_uint2(0u, 0u);
                const bool pre = (a + 1 < NA);
                if (pre) {
                    Pn = calc_params(a + 1);
                    if (stg) {
                        int soff = __float_as_int(Pn.w);
                        float fa = srowA[soff], fan = srowA[soff + 1];
                        float fb = srowB[soff], fbn = srowB[soff + 1];
                        stage_val = make_uint2(pkrtz_u32(fa, fb),
                                               pkrtz_u32(fan - fa, fbn - fb));
                    }
                }

                const float sy = P.y;
                const float tb = fmaf(px, P.x, fmaf(pyf, sy, P.z));
                #pragma unroll
                for (int k = 0; k < PXT; k++) {
                    float t  = fmaf((float)k, sy, tb);
                    int   i0 = (int)t;                    // t > 0 -> trunc == floor
#if __has_builtin(__builtin_amdgcn_fractf)
                    float w  = __builtin_amdgcn_fractf(t);
#else
                    float w  = t - (float)i0;
#endif
                    __half2 wh2 = u32_to_h2(pkrtz_u32(w, w));   // one pkrtz
                    const uint4 pk = win[p][i0];                // ds_read_b128
                    hacc01[k] = __hadd2(hacc01[k], u32_to_h2(pk.x));        // += (f0,f1)
                    hacc01[k] = __hfma2(wh2, u32_to_h2(pk.y), hacc01[k]);   // += w*(df0,df1)
                    hacc23[k] = __hadd2(hacc23[k], u32_to_h2(pk.z));        // += (f2,f3)
                    hacc23[k] = __hfma2(wh2, u32_to_h2(pk.w), hacc23[k]);   // += w*(df2,df3)
                }

                if (pre && stg)
                    ((uint2*)&win[p ^ 1][si])[sg] = stage_val;
                P = Pn;
                __syncthreads();
            }
        }
        // flush fp16 group accumulators into fp32
        #pragma unroll
        for (int k = 0; k < PXT; k++) {
            float2 v01 = __half22float2(hacc01[k]);
            float2 v23 = __half22float2(hacc23[k]);
            acc0[k] += v01.x; acc1[k] += v01.y;
            acc2[k] += v23.x; acc3[k] += v23.y;
            hacc01[k] = u32_to_h2(0u); hacc23[k] = u32_to_h2(0u);
        }
    }

    const float SCALE = (float)(M_PI / (double)NA);
    const size_t bstride = (size_t)NH * NW;
    size_t o0 = (((size_t)(bz * NBT) * NH) + (by * TH + ty0)) * NW + (bx * TW + tx);
    #pragma unroll
    for (int k = 0; k < PXT; k++) {
        img[o0 + (size_t)k * NW]               = acc0[k] * SCALE;
        img[o0 + (size_t)k * NW + bstride]     = acc1[k] * SCALE;
        img[o0 + (size_t)k * NW + 2 * bstride] = acc2[k] * SCALE;
        img[o0 + (size_t)k * NW + 3 * bstride] = acc3[k] * SCALE;
    }
}

// ---------------------------------------------------------------------------
extern "C" void kernel_launch(void* const* d_in, const int* in_sizes, int n_in,
                              void* d_out, int out_size, void* d_ws, size_t ws_size,
                              hipStream_t stream) {
    const float* sino = (const float*)d_in[0];
    const float* filt = (const float*)d_in[1];
    float* out = (float*)d_out;

    const size_t filt_bytes = (size_t)NB * NA * ND * sizeof(float);
    float* filtered;
    float2* cs_tab;
    if (ws_size >= filt_bytes + 4096) {
        filtered = (float*)d_ws;
        cs_tab = (float2*)((char*)d_ws + filt_bytes);
    } else {
        // fallback: filter in-place into the input (harness restores inputs
        // from a pristine copy before every launch)
        filtered = (float*)d_in[0];
        cs_tab = (float2*)d_ws;
    }

    angle_kernel<<<dim3(3), dim3(256), 0, stream>>>(cs_tab);
    filter_kernel<<<dim3(NB * NA / 2), dim3(256), 0, stream>>>(sino, filt, filtered);
    backproj_kernel<<<dim3(NW / TW, NH / TH, NB / NBT), dim3(256), 0, stream>>>(filtered, cs_tab, out);
}

// Round 11
// 574.755 us; speedup vs baseline: 12.5231x; 1.0790x over previous
//
#include <hip/hip_runtime.h>
#include <hip/hip_fp16.h>
#include <math.h>

#define NB 16
#define NA 720
#define ND 1024
#define NH 512
#define NW 512

#define TW 64      // tile width  (x)
#define TH 16      // tile height (y)
#define PXT 4      // y-pixels per thread
#define NBT 4      // batches per block
#define WINN 96    // window entries/batch (span <= sqrt(63^2+15^2)+3 ~ 68)
#define GROUP 16   // angles per fp16-accumulate group (720 = 45*16)

typedef __fp16 h2vec __attribute__((ext_vector_type(2)));

__device__ __forceinline__ uint32_t pkrtz_u32(float a, float b) {
    union { h2vec h; uint32_t u; } v;
    v.h = __builtin_amdgcn_cvt_pkrtz(a, b);   // one v_cvt_pkrtz_f16_f32
    return v.u;
}
__device__ __forceinline__ __half2 u32_to_h2(uint32_t u) {
    union { uint32_t u; __half2 h; } v; v.u = u; return v.h;
}

// ---------------------------------------------------------------------------
// Kernel 0: per-angle cos/sin table (matches jnp.linspace(0, pi, A, endpoint=False))
// ---------------------------------------------------------------------------
__global__ __launch_bounds__(256) void angle_kernel(float2* __restrict__ cs) {
    int a = blockIdx.x * 256 + threadIdx.x;
    if (a < NA) {
        const float step = (float)(M_PI / (double)NA);
        float ang = (float)a * step;
        float s, c;
        sincosf(ang, &s, &c);
        cs[a] = make_float2(c, s);
    }
}

// ---------------------------------------------------------------------------
// Kernel 1: ramp filter via in-LDS Stockham radix-2 FFT (fp32), TWO real rows
// per block packed as z = x0 + i*x1. Filter is real & even-symmetric, so
// Y = filt*Z directly; IFFT gives y0 = Re, y1 = Im. 1/ND ifft-norm folded in
// (pi/NA applied at backproj epilogue to keep fp16 staging well-scaled).
// ---------------------------------------------------------------------------
__global__ __launch_bounds__(256) void filter_kernel(const float* __restrict__ sino,
                                                     const float* __restrict__ filt,
                                                     float* __restrict__ outp) {
    __shared__ float2 bufA[ND];
    __shared__ float2 bufB[ND];
    __shared__ float2 tw[ND / 2];   // tw[m] = exp(-2*pi*i*m/ND)

    const int tid = threadIdx.x;
    const size_t r0 = (size_t)blockIdx.x * 2;
    const float* __restrict__ xa = sino + r0 * ND;
    const float* __restrict__ xb = xa + ND;
    float* __restrict__ ya = outp + r0 * ND;
    float* __restrict__ yb = ya + ND;

    #pragma unroll
    for (int i = 0; i < ND; i += 256)
        bufA[i + tid] = make_float2(xa[i + tid], xb[i + tid]);
    #pragma unroll
    for (int i = 0; i < ND / 2; i += 256) {
        int m = i + tid;
        float ang = (float)(-2.0 * M_PI / (double)ND) * (float)m;
        float s, c;
        sincosf(ang, &s, &c);
        tw[m] = make_float2(c, s);
    }
    __syncthreads();

    float2* src = bufA;
    float2* dst = bufB;

    // forward FFT: Stockham, Ns = 1..512
    for (int Ns = 1; Ns < ND; Ns <<= 1) {
        #pragma unroll
        for (int q = 0; q < ND / 2; q += 256) {
            int j = q + tid;
            int m = j & (Ns - 1);
            float2 v0 = src[j];
            float2 v1 = src[j + ND / 2];
            float2 w = tw[m * (ND / 2 / Ns)];
            float tr = w.x * v1.x - w.y * v1.y;
            float ti = w.x * v1.y + w.y * v1.x;
            int d = ((j & ~(Ns - 1)) << 1) + m;
            dst[d]      = make_float2(v0.x + tr, v0.y + ti);
            dst[d + Ns] = make_float2(v0.x - tr, v0.y - ti);
        }
        __syncthreads();
        float2* tmp = src; src = dst; dst = tmp;
    }

    // multiply by real filter, with 1/ND folded in
    const float SCALE = 1.0f / (float)ND;
    #pragma unroll
    for (int i = 0; i < ND; i += 256) {
        float f = filt[i + tid] * SCALE;
        src[i + tid].x *= f;
        src[i + tid].y *= f;
    }
    __syncthreads();

    // inverse FFT: same flow with conjugated twiddles
    for (int Ns = 1; Ns < ND; Ns <<= 1) {
        #pragma unroll
        for (int q = 0; q < ND / 2; q += 256) {
            int j = q + tid;
            int m = j & (Ns - 1);
            float2 v0 = src[j];
            float2 v1 = src[j + ND / 2];
            float2 w = tw[m * (ND / 2 / Ns)];
            float tr = w.x * v1.x + w.y * v1.y;   // conj(w)*v1
            float ti = w.x * v1.y - w.y * v1.x;
            int d = ((j & ~(Ns - 1)) << 1) + m;
            dst[d]      = make_float2(v0.x + tr, v0.y + ti);
            dst[d + Ns] = make_float2(v0.x - tr, v0.y - ti);
        }
        __syncthreads();
        float2* tmp = src; src = dst; dst = tmp;
    }

    #pragma unroll
    for (int i = 0; i < ND; i += 256) {
        ya[i + tid] = src[i + tid].x;   // row r0   (Re)
        yb[i + tid] = src[i + tid].y;   // row r0+1 (Im)
    }
}

// ---------------------------------------------------------------------------
// Kernel 2: backprojection. 64x16 tile x 4 BATCHES per 256-thread block.
// TWO 8B-stride window arrays (R9's measured-conflict-free layout; R10's
// 16B-stride b128 caused 3.1e7 bank conflicts):
//   win01[p][i] = (h f_b0, h f_b1 | h df_b0, h df_b1)
//   win23[p][i] = (h f_b2, h f_b3 | h df_b2, h df_b3)
// Two ds_read_b64 + 4 pk-fp16 ops serve FOUR batches' lerp-accumulates.
// DEPTH-2 staging pipeline: round a issues global loads for angle a+2 into
// registers, writes the previously-loaded angle a+1 into phase (a+1)&1, and
// computes angle a from phase a&1 — the L2-hit latency of the staging load
// gets a full round of slack instead of sitting on the barrier path.
// Shallow unroll only (R8's 16-angle unroll spilled to scratch).
// fp16 acc flushed to fp32 every GROUP=16 angles (group |sum| <= ~48).
// Bounds check eliminated: |px*c+py*s| <= 361.3 < 511.5.
// ---------------------------------------------------------------------------
__global__ __launch_bounds__(256, 4) void backproj_kernel(const float* __restrict__ filtered,
                                                          const float2* __restrict__ cs_tab,
                                                          float* __restrict__ img) {
    __shared__ __align__(16) uint2 win01[2][WINN];   // 1.5 KB
    __shared__ __align__(16) uint2 win23[2][WINN];   // 1.5 KB

    const int tid = threadIdx.x;
    const int bx = blockIdx.x, by = blockIdx.y, bz = blockIdx.z;

    const float x0 = (float)(bx * TW) - 255.5f;
    const float x1 = x0 + (float)(TW - 1);
    const float y0 = (float)(by * TH) - 255.5f;

    // per-angle params, block-uniform: (c, s, 511.5-base, bits(a*ND+base))
    // s >= 0 for angles in [0, pi) -> min over y at y0.
    auto calc_params = [&](int a) -> float4 {
        float2 cs = cs_tab[a];
        float tmin = 511.5f + fminf(x0 * cs.x, x1 * cs.x) + y0 * cs.y;
        int base = (int)floorf(tmin) - 1;
        return make_float4(cs.x, cs.y, 511.5f - (float)base,
                           __int_as_float(a * ND + base));
    };

    // staging: threads 0..191; sg selects batch pair (0: b0,b1 / 1: b2,b3),
    // si = window entry. One ds_write_b64 per thread per angle.
    const bool stg = tid < 2 * WINN;
    const int sg   = (tid >= WINN) ? 1 : 0;
    const int si   = tid - sg * WINN;
    const float* __restrict__ srowA =
        filtered + (size_t)(bz * NBT + 2 * sg) * NA * ND + si;
    const float* __restrict__ srowB = srowA + (size_t)NA * ND;
    uint2* const wptr = (sg ? &win23[0][0] : &win01[0][0]) + si;

    const int tx  = tid & (TW - 1);
    const int ty0 = (tid >> 6) * PXT;
    const float px  = (float)(bx * TW + tx)  - 255.5f;
    const float pyf = (float)(by * TH + ty0) - 255.5f;

    float acc0[PXT], acc1[PXT], acc2[PXT], acc3[PXT];
    __half2 hacc01[PXT], hacc23[PXT];
    #pragma unroll
    for (int k = 0; k < PXT; k++) {
        acc0[k] = 0.0f; acc1[k] = 0.0f; acc2[k] = 0.0f; acc3[k] = 0.0f;
        hacc01[k] = u32_to_h2(0u); hacc23[k] = u32_to_h2(0u);
    }

    // prologue: stage angle 0 into phase 0 (immediate); load angle 1 into regs
    float4 P  = calc_params(0);
    float4 Pn = calc_params(1);
    float ha = 0.0f, han = 0.0f, hb = 0.0f, hbn = 0.0f;   // held raw (angle a+1)
    if (stg) {
        int s0 = __float_as_int(P.w);
        float fa = srowA[s0], fan = srowA[s0 + 1];
        float fb = srowB[s0], fbn = srowB[s0 + 1];
        wptr[0] = make_uint2(pkrtz_u32(fa, fb), pkrtz_u32(fan - fa, fbn - fb));
        int s1 = __float_as_int(Pn.w);
        ha = srowA[s1]; han = srowA[s1 + 1];
        hb = srowB[s1]; hbn = srowB[s1 + 1];
    }
    __syncthreads();

    for (int g = 0; g < NA; g += GROUP) {
        for (int a0 = 0; a0 < GROUP; a0 += 2) {
            #pragma unroll
            for (int p = 0; p < 2; p++) {
                const int a = g + a0 + p;

                // 1) issue staging loads for angle a+2 (consumed next round)
                float4 Pnn = Pn;
                float la = 0.0f, lan = 0.0f, lb = 0.0f, lbn = 0.0f;
                if (a + 2 < NA) {
                    Pnn = calc_params(a + 2);
                    if (stg) {
                        int s2 = __float_as_int(Pnn.w);
                        la = srowA[s2]; lan = srowA[s2 + 1];
                        lb = srowB[s2]; lbn = srowB[s2 + 1];
                    }
                }

                // 2) write the held angle a+1 into phase p^1 (loads had a
                //    full round of slack -> vmcnt wait is off the hot path)
                if (stg && (a + 1 < NA))
                    wptr[(p ^ 1) * WINN] =
                        make_uint2(pkrtz_u32(ha, hb),
                                   pkrtz_u32(han - ha, hbn - hb));

                // 3) compute angle a from phase p
                const float sy = P.y;
                const float tb = fmaf(px, P.x, fmaf(pyf, sy, P.z));
                #pragma unroll
                for (int k = 0; k < PXT; k++) {
                    float t  = fmaf((float)k, sy, tb);
                    int   i0 = (int)t;                    // t > 0 -> trunc == floor
#if __has_builtin(__builtin_amdgcn_fractf)
                    float w  = __builtin_amdgcn_fractf(t);
#else
                    float w  = t - (float)i0;
#endif
                    __half2 wh2 = u32_to_h2(pkrtz_u32(w, w));   // one pkrtz
                    const uint2 q01 = win01[p][i0];             // ds_read_b64
                    const uint2 q23 = win23[p][i0];             // ds_read_b64
                    hacc01[k] = __hadd2(hacc01[k], u32_to_h2(q01.x));
                    hacc01[k] = __hfma2(wh2, u32_to_h2(q01.y), hacc01[k]);
                    hacc23[k] = __hadd2(hacc23[k], u32_to_h2(q23.x));
                    hacc23[k] = __hfma2(wh2, u32_to_h2(q23.y), hacc23[k]);
                }

                // 4) rotate pipeline state
                ha = la; han = lan; hb = lb; hbn = lbn;
                P = Pn; Pn = Pnn;
                __syncthreads();
            }
        }
        // flush fp16 group accumulators into fp32
        #pragma unroll
        for (int k = 0; k < PXT; k++) {
            float2 v01 = __half22float2(hacc01[k]);
            float2 v23 = __half22float2(hacc23[k]);
            acc0[k] += v01.x; acc1[k] += v01.y;
            acc2[k] += v23.x; acc3[k] += v23.y;
            hacc01[k] = u32_to_h2(0u); hacc23[k] = u32_to_h2(0u);
        }
    }

    const float SCALE = (float)(M_PI / (double)NA);
    const size_t bstride = (size_t)NH * NW;
    size_t o0 = (((size_t)(bz * NBT) * NH) + (by * TH + ty0)) * NW + (bx * TW + tx);
    #pragma unroll
    for (int k = 0; k < PXT; k++) {
        img[o0 + (size_t)k * NW]               = acc0[k] * SCALE;
        img[o0 + (size_t)k * NW + bstride]     = acc1[k] * SCALE;
        img[o0 + (size_t)k * NW + 2 * bstride] = acc2[k] * SCALE;
        img[o0 + (size_t)k * NW + 3 * bstride] = acc3[k] * SCALE;
    }
}

// ---------------------------------------------------------------------------
extern "C" void kernel_launch(void* const* d_in, const int* in_sizes, int n_in,
                              void* d_out, int out_size, void* d_ws, size_t ws_size,
                              hipStream_t stream) {
    const float* sino = (const float*)d_in[0];
    const float* filt = (const float*)d_in[1];
    float* out = (float*)d_out;

    const size_t filt_bytes = (size_t)NB * NA * ND * sizeof(float);
    float* filtered;
    float2* cs_tab;
    if (ws_size >= filt_bytes + 4096) {
        filtered = (float*)d_ws;
        cs_tab = (float2*)((char*)d_ws + filt_bytes);
    } else {
        // fallback: filter in-place into the input (harness restores inputs
        // from a pristine copy before every launch)
        filtered = (float*)d_in[0];
        cs_tab = (float2*)d_ws;
    }

    angle_kernel<<<dim3(3), dim3(256), 0, stream>>>(cs_tab);
    filter_kernel<<<dim3(NB * NA / 2), dim3(256), 0, stream>>>(sino, filt, filtered);
    backproj_kernel<<<dim3(NW / TW, NH / TH, NB / NBT), dim3(256), 0, stream>>>(filtered, cs_tab, out);
}

// Round 12
// 451.766 us; speedup vs baseline: 15.9324x; 1.2722x over previous
//
#include <hip/hip_runtime.h>
#include <hip/hip_fp16.h>
#include <math.h>

#define NB 16
#define NA 720
#define ND 1024
#define NH 512
#define NW 512

#define TW 64      // tile width  (x)
#define TH 16      // tile height (y)
#define PXT 4      // y-pixels per thread
#define NBT 4      // batches per block
#define WINN 96    // window entries/batch-pair (span <= sqrt(63^2+15^2)+3 ~ 68)
#define GROUP 16   // angles per fp16-accumulate group (720 = 45*16)

typedef __fp16 h2vec __attribute__((ext_vector_type(2)));

__device__ __forceinline__ uint32_t pkrtz_u32(float a, float b) {
    union { h2vec h; uint32_t u; } v;
    v.h = __builtin_amdgcn_cvt_pkrtz(a, b);   // one v_cvt_pkrtz_f16_f32
    return v.u;
}
__device__ __forceinline__ __half2 u32_to_h2(uint32_t u) {
    union { uint32_t u; __half2 h; } v; v.u = u; return v.h;
}
__device__ __forceinline__ uint32_t h2_to_u32(__half2 h) {
    union { __half2 h; uint32_t u; } v; v.h = h; return v.u;
}

// ---------------------------------------------------------------------------
// Kernel 0: per-(tile-position, angle) parameter table. 256 positions x 720
// angles x 16B. Entry: (c, s, 511.5-base, bits(a*ND+base)). Computed once so
// the backproj kernel reads params via uniform s_load (SMEM pipe) instead of
// re-deriving them in VALU every angle (no scalar FP unit on CDNA).
// ---------------------------------------------------------------------------
__global__ __launch_bounds__(768) void prep_kernel(float4* __restrict__ ptable) {
    const int a = threadIdx.x;
    const int pos = blockIdx.x;
    if (a >= NA) return;
    const float step = (float)(M_PI / (double)NA);
    float s, c;
    sincosf((float)a * step, &s, &c);
    const int bx = pos & 7, by = pos >> 3;
    const float x0 = (float)(bx * TW) - 255.5f;
    const float x1 = x0 + (float)(TW - 1);
    const float y0 = (float)(by * TH) - 255.5f;
    // s >= 0 for angles in [0, pi): min over y at y0.
    const float tmin = 511.5f + fminf(x0 * c, x1 * c) + y0 * s;
    const int base = (int)floorf(tmin) - 1;
    ptable[pos * NA + a] = make_float4(c, s, 511.5f - (float)base,
                                       __int_as_float(a * ND + base));
}

// ---------------------------------------------------------------------------
// Kernel 1: ramp filter via in-LDS Stockham radix-2 FFT (fp32). Pairs the two
// rows of a BATCH-PAIR at the SAME angle: z = x_{2p} + i*x_{2p+1}; filter is
// real & even-symmetric so Y = filt*Z; IFFT -> Re = batch 2p, Im = batch 2p+1.
// Output is fp16-PACKED u32 (h(f_2p[i]), h(f_2p+1[i])) written into the row
// slot of batch 2p, angle a -- block-local in-place safe for the d_in[0]
// fallback (reads complete into LDS before stores). 1/ND norm folded in.
// ---------------------------------------------------------------------------
__global__ __launch_bounds__(256) void filter_kernel(const float* __restrict__ sino,
                                                     const float* __restrict__ filt,
                                                     uint32_t* __restrict__ packed) {
    __shared__ float2 bufA[ND];
    __shared__ float2 bufB[ND];
    __shared__ float2 tw[ND / 2];   // tw[m] = exp(-2*pi*i*m/ND)

    const int tid = threadIdx.x;
    const int a = blockIdx.x;       // angle
    const int p = blockIdx.y;       // batch pair
    const float* __restrict__ xa = sino + ((size_t)(2 * p) * NA + a) * ND;
    const float* __restrict__ xb = xa + (size_t)NA * ND;
    uint32_t* __restrict__ yo = packed + ((size_t)(2 * p) * NA + a) * ND;

    #pragma unroll
    for (int i = 0; i < ND; i += 256)
        bufA[i + tid] = make_float2(xa[i + tid], xb[i + tid]);
    #pragma unroll
    for (int i = 0; i < ND / 2; i += 256) {
        int m = i + tid;
        float ang = (float)(-2.0 * M_PI / (double)ND) * (float)m;
        float s, c;
        sincosf(ang, &s, &c);
        tw[m] = make_float2(c, s);
    }
    __syncthreads();

    float2* src = bufA;
    float2* dst = bufB;

    // forward FFT: Stockham, Ns = 1..512
    for (int Ns = 1; Ns < ND; Ns <<= 1) {
        #pragma unroll
        for (int q = 0; q < ND / 2; q += 256) {
            int j = q + tid;
            int m = j & (Ns - 1);
            float2 v0 = src[j];
            float2 v1 = src[j + ND / 2];
            float2 w = tw[m * (ND / 2 / Ns)];
            float tr = w.x * v1.x - w.y * v1.y;
            float ti = w.x * v1.y + w.y * v1.x;
            int d = ((j & ~(Ns - 1)) << 1) + m;
            dst[d]      = make_float2(v0.x + tr, v0.y + ti);
            dst[d + Ns] = make_float2(v0.x - tr, v0.y - ti);
        }
        __syncthreads();
        float2* tmp = src; src = dst; dst = tmp;
    }

    // multiply by real filter, with 1/ND folded in
    const float SCALE = 1.0f / (float)ND;
    #pragma unroll
    for (int i = 0; i < ND; i += 256) {
        float f = filt[i + tid] * SCALE;
        src[i + tid].x *= f;
        src[i + tid].y *= f;
    }
    __syncthreads();

    // inverse FFT: same flow with conjugated twiddles
    for (int Ns = 1; Ns < ND; Ns <<= 1) {
        #pragma unroll
        for (int q = 0; q < ND / 2; q += 256) {
            int j = q + tid;
            int m = j & (Ns - 1);
            float2 v0 = src[j];
            float2 v1 = src[j + ND / 2];
            float2 w = tw[m * (ND / 2 / Ns)];
            float tr = w.x * v1.x + w.y * v1.y;   // conj(w)*v1
            float ti = w.x * v1.y - w.y * v1.x;
            int d = ((j & ~(Ns - 1)) << 1) + m;
            dst[d]      = make_float2(v0.x + tr, v0.y + ti);
            dst[d + Ns] = make_float2(v0.x - tr, v0.y - ti);
        }
        __syncthreads();
        float2* tmp = src; src = dst; dst = tmp;
    }

    #pragma unroll
    for (int i = 0; i < ND; i += 256)
        yo[i + tid] = pkrtz_u32(src[i + tid].x, src[i + tid].y);
}

// ---------------------------------------------------------------------------
// Kernel 2: backprojection. 64x16 tile x 4 batches per 256-thread block.
// Params via uniform s_load from ptable (0 VALU). Staging reads PRE-PACKED
// fp16 pairs: 2 dword loads + 1 hsub2 + 1 ds_write_b64 per angle per thread.
// FOUR phases, TWO angles per barrier (360 barriers): sub-round A computes
// phases 0,1, writes held angles into 2,3, issues loads; sub-round B mirrors.
// Phases are compile-time; the it-loop is NOT unrolled (R8: deep unroll
// spills). Two 8B-stride window arrays (measured conflict-free):
//   win01[ph][i] = (f_b0|f_b1, df_b0|df_b1), win23 likewise for b2,b3.
// Inner loop: 2x ds_read_b64 + 4 pk-fp16 ops serve 4 batches' lerps.
// fp16 acc flushed to fp32 every GROUP=16 angles. Bounds check eliminated:
// |px*c+py*s| <= 361.3 < 511.5; local index in [1,70] subset of [0,94].
// ---------------------------------------------------------------------------
__global__ __launch_bounds__(256, 4) void backproj_kernel(const uint32_t* __restrict__ packed,
                                                          const float4* __restrict__ ptable,
                                                          float* __restrict__ img) {
    __shared__ __align__(16) uint2 win01[4][WINN];   // 3 KB
    __shared__ __align__(16) uint2 win23[4][WINN];   // 3 KB

    const int tid = threadIdx.x;
    const int bx = blockIdx.x, by = blockIdx.y, bz = blockIdx.z;

    const float4* __restrict__ pt = ptable + (size_t)((by << 3) + bx) * NA;

    // staging: threads 0..191; sg selects batch pair (0: b0,b1 / 1: b2,b3)
    const bool stg = tid < 2 * WINN;
    const int sg   = (tid >= WINN) ? 1 : 0;
    const int si   = tid - sg * WINN;
    // packed row slot of batch (2*pair), angle a, detector i:
    //   packed[((2*pair)*NA + a)*ND + i]
    const uint32_t* __restrict__ sbase =
        packed + (size_t)(2 * (bz * 2 + sg)) * NA * ND + si;
    uint2* const wptr = (sg ? &win23[0][0] : &win01[0][0]) + si;

    const int tx  = tid & (TW - 1);
    const int ty0 = (tid >> 6) * PXT;
    const float px  = (float)(bx * TW + tx)  - 255.5f;
    const float pyf = (float)(by * TH + ty0) - 255.5f;

    float acc0[PXT], acc1[PXT], acc2[PXT], acc3[PXT];
    __half2 hacc01[PXT], hacc23[PXT];
    #pragma unroll
    for (int k = 0; k < PXT; k++) {
        acc0[k] = 0.0f; acc1[k] = 0.0f; acc2[k] = 0.0f; acc3[k] = 0.0f;
        hacc01[k] = u32_to_h2(0u); hacc23[k] = u32_to_h2(0u);
    }

    auto stage_load = [&](float4 P, uint32_t& w0, uint32_t& w1) {
        const uint32_t* sp = sbase + __float_as_int(P.w);
        w0 = sp[0];
        w1 = sp[1];
    };
    auto stage_write = [&](int ph, uint32_t w0, uint32_t w1) {
        wptr[ph * WINN] = make_uint2(
            w0, h2_to_u32(__hsub2(u32_to_h2(w1), u32_to_h2(w0))));
    };
    auto compute = [&](float4 P, int ph) {
        const float sy = P.y;
        const float tb = fmaf(px, P.x, fmaf(pyf, sy, P.z));
        #pragma unroll
        for (int k = 0; k < PXT; k++) {
            float t  = fmaf((float)k, sy, tb);
            int   i0 = (int)t;                    // t > 0 -> trunc == floor
#if __has_builtin(__builtin_amdgcn_fractf)
            float w  = __builtin_amdgcn_fractf(t);
#else
            float w  = t - (float)i0;
#endif
            __half2 wh2 = u32_to_h2(pkrtz_u32(w, w));   // one pkrtz
            const uint2 q01 = win01[ph][i0];            // ds_read_b64
            const uint2 q23 = win23[ph][i0];            // ds_read_b64
            hacc01[k] = __hadd2(hacc01[k], u32_to_h2(q01.x));
            hacc01[k] = __hfma2(wh2, u32_to_h2(q01.y), hacc01[k]);
            hacc23[k] = __hadd2(hacc23[k], u32_to_h2(q23.x));
            hacc23[k] = __hfma2(wh2, u32_to_h2(q23.y), hacc23[k]);
        }
    };

    // prologue: stage angles 0,1 into phases 0,1; hold raw loads of 2,3
    uint32_t h2w0 = 0, h2w1 = 0, h3w0 = 0, h3w1 = 0;
    if (stg) {
        uint32_t w0, w1;
        stage_load(pt[0], w0, w1);  stage_write(0, w0, w1);
        stage_load(pt[1], w0, w1);  stage_write(1, w0, w1);
        stage_load(pt[2], h2w0, h2w1);
        stage_load(pt[3], h3w0, h3w1);
    }
    __syncthreads();

    for (int g = 0; g < NA; g += GROUP) {
        #pragma unroll 1
        for (int it = 0; it < GROUP / 4; it++) {
            const int a = g + it * 4;
            // params a..a+7 via uniform s_load (a+4.. clamped; only .w used
            // for staging addresses of angles that are never computed OOB)
            const float4 P0 = pt[a],     P1 = pt[a + 1];
            const float4 P2 = pt[a + 2], P3 = pt[a + 3];
            const float4 P4 = pt[min(a + 4, NA - 1)], P5 = pt[min(a + 5, NA - 1)];
            const float4 P6 = pt[min(a + 6, NA - 1)], P7 = pt[min(a + 7, NA - 1)];

            // ---- sub-round A: compute a, a+1 (ph 0,1) ----
            uint32_t l4w0 = 0, l4w1 = 0, l5w0 = 0, l5w1 = 0;
            if (stg) {
                stage_load(P4, l4w0, l4w1);      // angle a+4 (consumed in B)
                stage_load(P5, l5w0, l5w1);      // angle a+5
                stage_write(2, h2w0, h2w1);      // angle a+2 -> ph2
                stage_write(3, h3w0, h3w1);      // angle a+3 -> ph3
            }
            compute(P0, 0);
            compute(P1, 1);
            __syncthreads();

            // ---- sub-round B: compute a+2, a+3 (ph 2,3) ----
            uint32_t l6w0 = 0, l6w1 = 0, l7w0 = 0, l7w1 = 0;
            if (stg) {
                stage_load(P6, l6w0, l6w1);      // angle a+6 (held to next it)
                stage_load(P7, l7w0, l7w1);      // angle a+7
                stage_write(0, l4w0, l4w1);      // angle a+4 -> ph0
                stage_write(1, l5w0, l5w1);      // angle a+5 -> ph1
            }
            compute(P2, 2);
            compute(P3, 3);
            h2w0 = l6w0; h2w1 = l6w1; h3w0 = l7w0; h3w1 = l7w1;
            __syncthreads();
        }
        // flush fp16 group accumulators into fp32
        #pragma unroll
        for (int k = 0; k < PXT; k++) {
            float2 v01 = __half22float2(hacc01[k]);
            float2 v23 = __half22float2(hacc23[k]);
            acc0[k] += v01.x; acc1[k] += v01.y;
            acc2[k] += v23.x; acc3[k] += v23.y;
            hacc01[k] = u32_to_h2(0u); hacc23[k] = u32_to_h2(0u);
        }
    }

    const float SCALE = (float)(M_PI / (double)NA);
    const size_t bstride = (size_t)NH * NW;
    size_t o0 = (((size_t)(bz * NBT) * NH) + (by * TH + ty0)) * NW + (bx * TW + tx);
    #pragma unroll
    for (int k = 0; k < PXT; k++) {
        img[o0 + (size_t)k * NW]               = acc0[k] * SCALE;
        img[o0 + (size_t)k * NW + bstride]     = acc1[k] * SCALE;
        img[o0 + (size_t)k * NW + 2 * bstride] = acc2[k] * SCALE;
        img[o0 + (size_t)k * NW + 3 * bstride] = acc3[k] * SCALE;
    }
}

// ---------------------------------------------------------------------------
extern "C" void kernel_launch(void* const* d_in, const int* in_sizes, int n_in,
                              void* d_out, int out_size, void* d_ws, size_t ws_size,
                              hipStream_t stream) {
    const float* sino = (const float*)d_in[0];
    const float* filt = (const float*)d_in[1];
    float* out = (float*)d_out;

    // packed buffer occupies the even-batch row slots of a full-size
    // (NB*NA*ND u32) region — same footprint as the old fp32 filtered buffer.
    const size_t pack_bytes = (size_t)NB * NA * ND * sizeof(uint32_t);
    const size_t ptab_bytes = (size_t)256 * NA * sizeof(float4);
    uint32_t* packed;
    float4* ptable;
    if (ws_size >= pack_bytes + ptab_bytes) {
        packed = (uint32_t*)d_ws;
        ptable = (float4*)((char*)d_ws + pack_bytes);
    } else {
        // fallback: pack in-place into the input (filter writes are
        // block-local: each block overwrites only the row it read) and put
        // the params table in d_ws.
        packed = (uint32_t*)d_in[0];
        ptable = (float4*)d_ws;
    }

    prep_kernel<<<dim3(256), dim3(768), 0, stream>>>(ptable);
    filter_kernel<<<dim3(NA, NB / 2), dim3(256), 0, stream>>>(sino, filt, packed);
    backproj_kernel<<<dim3(NW / TW, NH / TH, NB / NBT), dim3(256), 0, stream>>>(packed, ptable, out);
}